// Round 8
// baseline (304.168 us; speedup 1.0000x reference)
//
#include <hip/hip_runtime.h>

#define EPSV 1e-5f
#define NBLK 512

typedef short bf16x8 __attribute__((ext_vector_type(8)));
typedef float f32x4 __attribute__((ext_vector_type(4)));

static __device__ __forceinline__ unsigned short f2b(float f) {
  union { float f; unsigned u; } v; v.f = f;
  return (unsigned short)((v.u + 0x7fffu + ((v.u >> 16) & 1u)) >> 16);
}

// Grid barrier without cooperative launch; all NBLK blocks co-resident by
// construction (512 = 2/CU x 256 CU, launch_bounds(256,2), 17.4KB LDS).
// R6 lesson: full-rate acquire polling saturates the fabric. v2 throttles
// with s_sleep (~1000 cyc/poll, ~100x less traffic), polls RELAXED, and
// issues ONE acquire fence on exit. Bounded spin: failure -> wrong answer,
// never a harness hang.
static __device__ __forceinline__ void gbar(int* bar) {
  __syncthreads();
  if (threadIdx.x == 0) {
    __hip_atomic_fetch_add(bar, 1, __ATOMIC_RELEASE, __HIP_MEMORY_SCOPE_AGENT);
    for (int it = 0; it < (1 << 22); ++it) {
      if (__hip_atomic_load(bar, __ATOMIC_RELAXED, __HIP_MEMORY_SCOPE_AGENT) >= NBLK)
        break;
      __builtin_amdgcn_s_sleep(16);
    }
    __builtin_amdgcn_fence(__ATOMIC_ACQUIRE, "agent");
  }
  __syncthreads();
}

// One kernel, 512 blocks x 256 threads, phases split by sleep-barriers:
//  P1: zero out + Wfc->bf16 swizzle (all) + x col partial stats (blk<256)
//  P3: fin1 inline (once per block) + layer-2 preact stats, 2 tiles/block
//  P4: BN2 finalize distributed 8 c2/block -> pt rows 16..51
//  P5: fused A-gen + bf16 MFMA GEMM (R4 body: BM=64, K-split=4, atomic merge)
// pt layout [param i][d]: 0..7=s1_i, 8..15=t1_i, 16..47=W2s(o*8+i), 48..51=t2c
// wb frag layout: frag=k32b*16+nb; lane(quad,l15): n=nb*16+l15, k=k32b*32+quad*8
__global__ __launch_bounds__(256, 2) void k_all(
    const float* __restrict__ x, const float* __restrict__ W1,
    const float* __restrict__ g1, const float* __restrict__ be1,
    const float* __restrict__ W2, const float* __restrict__ g2,
    const float* __restrict__ be2, const float* __restrict__ wfc,
    const float* __restrict__ bfc, unsigned short* __restrict__ wb,
    float* __restrict__ pt, float* __restrict__ ps1,
    float* __restrict__ ps2s, float* __restrict__ ps2q,
    int* __restrict__ bars, float* __restrict__ out) {
  __shared__ __align__(16) unsigned char smem[64 * 136 * 2];  // 17408 B union
  const int t = threadIdx.x;
  const int blk = blockIdx.x;

  // ---------------- P1 ----------------
  {
    const size_t gid = (size_t)blk * 256 + t;
    float4 z4 = {0.f, 0.f, 0.f, 0.f};
    float4* ob = (float4*)(out + gid * 16);
#pragma unroll
    for (int j = 0; j < 4; ++j) ob[j] = z4;

    const int f = blk * 256 + t;                         // 0..131071
    const int l15 = f & 15, quad = (f >> 4) & 3, nb = (f >> 6) & 15, k32b = f >> 10;
    const int n = nb * 16 + l15;
    const int k = k32b * 32 + quad * 8;
    const float4* src = (const float4*)(wfc + (size_t)n * 4096 + k);
    float4 a = src[0], b = src[1];
    ushort4 o0, o1;
    o0.x = f2b(a.x); o0.y = f2b(a.y); o0.z = f2b(a.z); o0.w = f2b(a.w);
    o1.x = f2b(b.x); o1.y = f2b(b.y); o1.z = f2b(b.z); o1.w = f2b(b.w);
    *(ushort4*)(wb + (size_t)f * 8) = o0;
    *(ushort4*)(wb + (size_t)f * 8 + 4) = o1;

    if (blk < 256) {
      const int c = t * 4;
      const int r0 = blk * 32;
      float4 s = {0.f,0.f,0.f,0.f}, q = {0.f,0.f,0.f,0.f};
      for (int g = 0; g < 4; ++g) {
        float4 v[8];
#pragma unroll
        for (int j = 0; j < 8; ++j)
          v[j] = *(const float4*)(x + (size_t)(r0 + g*8 + j) * 1024 + c);
#pragma unroll
        for (int j = 0; j < 8; ++j) {
          s.x += v[j].x; s.y += v[j].y; s.z += v[j].z; s.w += v[j].w;
          q.x = fmaf(v[j].x, v[j].x, q.x); q.y = fmaf(v[j].y, v[j].y, q.y);
          q.z = fmaf(v[j].z, v[j].z, q.z); q.w = fmaf(v[j].w, v[j].w, q.w);
        }
      }
      *(float4*)(ps1 + (size_t)blk * 2048 + c) = s;
      *(float4*)(ps1 + (size_t)blk * 2048 + 1024 + c) = q;
    }
  }
  gbar(&bars[0]);

  // ---------------- P3: fin1 inline + h2 stats (2 tiles, same dgrp) --------
  {
    float* rs = (float*)smem;                              // [8][32]
    float* rq = (float*)(smem + 1024);                     // [8][32]
    float (*red)[32][8] = (float (*)[32][8])(smem + 2048); // 8 KB
    const int dl = t & 31, slot = t >> 5;
    const int dgrp = blk & 31;
    const int d = dgrp * 32 + dl;
    // fin1 inline: reduce 256 ps1 partials for this block's 32 d
    float s0 = 0.f, q0 = 0.f;
    for (int u = 0; u < 32; u += 4) {
#pragma unroll
      for (int w = 0; w < 4; ++w) {
        const size_t base = (size_t)(slot + (u + w) * 8) * 2048 + d;
        s0 += ps1[base];
        q0 += ps1[base + 1024];
      }
    }
    rs[slot * 32 + dl] = s0; rq[slot * 32 + dl] = q0;
    __syncthreads();
    float xs = 0.f, xq = 0.f;
#pragma unroll
    for (int p = 0; p < 8; ++p) { xs += rs[p * 32 + dl]; xq += rq[p * 32 + dl]; }
    const float inv = 1.f / 8192.f;
    const float mean = xs * inv;
    const float var = xq * inv - mean * mean;
    float s1v[8], t1v[8], w2v[32];
#pragma unroll
    for (int i = 0; i < 8; ++i) {
      const int c = d * 8 + i;
      float w = W1[c];
      s1v[i] = g1[c] * w * rsqrtf(w * w * var + EPSV);
      t1v[i] = be1[c] - s1v[i] * mean;
    }
    if (blk < 32 && slot == 0) {     // publish s1/t1 for P5 (blk==dgrp here)
#pragma unroll
      for (int i = 0; i < 8; ++i) {
        pt[i * 1024 + d] = s1v[i];
        pt[(8 + i) * 1024 + d] = t1v[i];
      }
    }
    const float4* wp = (const float4*)(W2 + (size_t)d * 32);
#pragma unroll
    for (int i = 0; i < 8; ++i) {
      float4 v = wp[i];
      w2v[i*4+0]=v.x; w2v[i*4+1]=v.y; w2v[i*4+2]=v.z; w2v[i*4+3]=v.w;
    }
#pragma unroll
    for (int it = 0; it < 2; ++it) {
      const int bgrp = (blk >> 5) + 16 * it;             // tile = blk + 512*it
      float s[4] = {0.f,0.f,0.f,0.f}, q[4] = {0.f,0.f,0.f,0.f};
      const int b0 = bgrp * 256 + slot * 32;
      for (int r = 0; r < 32; r += 8) {
        float xv[8];
#pragma unroll
        for (int j = 0; j < 8; ++j)
          xv[j] = x[(size_t)(b0 + r + j) * 1024 + d];
#pragma unroll
        for (int j = 0; j < 8; ++j) {
          float a1[8];
#pragma unroll
          for (int i = 0; i < 8; ++i) a1[i] = fmaxf(fmaf(s1v[i], xv[j], t1v[i]), 0.f);
#pragma unroll
          for (int o = 0; o < 4; ++o) {
            float h = 0.f;
#pragma unroll
            for (int i = 0; i < 8; ++i) h = fmaf(a1[i], w2v[o*8+i], h);
            s[o] += h;
            q[o] = fmaf(h, h, q[o]);
          }
        }
      }
      __syncthreads();   // WAR on red (and rs/rq region in it 0)
#pragma unroll
      for (int j = 0; j < 4; ++j) {
        red[slot][dl][j] = s[j];
        red[slot][dl][4+j] = q[j];
      }
      __syncthreads();
      const int d2l = t >> 3, j = t & 7;
      float v = 0.f;
#pragma unroll
      for (int p = 0; p < 8; ++p) v += red[p][d2l][j];
      const int c2 = (dgrp * 32 + d2l) * 4 + (t & 3);
      if (j < 4) ps2s[(size_t)bgrp * 4096 + c2] = v;
      else       ps2q[(size_t)bgrp * 4096 + c2] = v;
    }
  }
  gbar(&bars[1]);

  // ---------------- P4: BN2 finalize, distributed 8 c2/block ----------------
  {
    float (*r2)[8][2] = (float (*)[8][2])smem;           // [32][8][2]
    const int c2i = t & 7, p = t >> 3;
    const int c2 = blk * 8 + c2i;
    r2[p][c2i][0] = ps2s[(size_t)p * 4096 + c2];
    r2[p][c2i][1] = ps2q[(size_t)p * 4096 + c2];
    __syncthreads();
    if (t < 8) {
      const int c2g = blk * 8 + t;
      float sm = 0.f, sq = 0.f;
#pragma unroll
      for (int pp = 0; pp < 32; ++pp) { sm += r2[pp][t][0]; sq += r2[pp][t][1]; }
      const float inv = 1.f / 8192.f;
      float m = sm * inv;
      float var = sq * inv - m * m;
      float s2 = g2[c2g] * rsqrtf(var + EPSV);
      float t2 = be2[c2g] - s2 * m;
      const int d = c2g >> 2, o = c2g & 3;
      pt[(48 + o) * 1024 + d] = t2;
#pragma unroll
      for (int i = 0; i < 8; ++i)
        pt[(16 + o * 8 + i) * 1024 + d] = W2[(size_t)d * 32 + o * 8 + i] * s2;
    }
  }
  gbar(&bars[2]);

  // ---------------- P5: fused A-gen + GEMM (R4 body) ----------------
  {
    // As stride 136 shorts = 68 dwords (==4 mod 32): b128 reads tile banks evenly
    unsigned short* As = (unsigned short*)smem;
    const int lane = t & 63;
    const int wv = t >> 6;
    const int mt0 = blk & 127;
    const int kQ = blk >> 7;                             // 0..3
    const int m0 = mt0 * 64;
    const int d0 = kQ * 256;
    const int quad = lane >> 4;
    const int l15 = lane & 15;
    const int dl = t & 31, bs = t >> 5;
    const int chrot = (mt0 & 1) << 2;

    f32x4 acc[4][4];
#pragma unroll
    for (int mt = 0; mt < 4; ++mt)
#pragma unroll
      for (int nt = 0; nt < 4; ++nt) {
        f32x4 z = {0.f, 0.f, 0.f, 0.f};
        acc[mt][nt] = z;
      }

    for (int chi = 0; chi < 8; ++chi) {
      const int ch = (chi + chrot) & 7;
      const int d = d0 + ch * 32 + dl;
      float pv[52];
#pragma unroll
      for (int i = 0; i < 52; ++i) pv[i] = pt[i * 1024 + d];
      __syncthreads();   // previous MFMA phase done reading As
#pragma unroll
      for (int r = 0; r < 8; ++r) {
        const int bl = bs * 8 + r;
        float xv = x[(size_t)(m0 + bl) * 1024 + d];
        float a1[8];
#pragma unroll
        for (int i = 0; i < 8; ++i) a1[i] = fmaxf(fmaf(pv[i], xv, pv[8+i]), 0.f);
        unsigned short o4[4];
#pragma unroll
        for (int o = 0; o < 4; ++o) {
          float h = pv[48 + o];
#pragma unroll
          for (int i = 0; i < 8; ++i) h = fmaf(a1[i], pv[16 + o*8 + i], h);
          o4[o] = f2b(fmaxf(h, 0.f));
        }
        *(ushort4*)&As[bl * 136 + dl * 4] = make_ushort4(o4[0], o4[1], o4[2], o4[3]);
      }
      __syncthreads();
#pragma unroll
      for (int kk = 0; kk < 4; ++kk) {
        bf16x8 af[4];
#pragma unroll
        for (int mt = 0; mt < 4; ++mt)
          af[mt] = *(const bf16x8*)&As[(mt*16 + l15) * 136 + kk*32 + quad*8];
        const int k32b = kQ * 32 + ch * 4 + kk;
#pragma unroll
        for (int nt = 0; nt < 4; ++nt) {
          const int frag = k32b * 16 + wv * 4 + nt;
          bf16x8 bfr = *(const bf16x8*)&wb[((size_t)frag * 64 + lane) * 8];
#pragma unroll
          for (int mt = 0; mt < 4; ++mt)
            acc[mt][nt] = __builtin_amdgcn_mfma_f32_16x16x32_bf16(af[mt], bfr,
                                                                  acc[mt][nt], 0, 0, 0);
        }
      }
    }
#pragma unroll
    for (int nt = 0; nt < 4; ++nt) {
      const int col = wv * 64 + nt * 16 + l15;
      const float bias = (kQ == 0) ? bfc[col] : 0.f;
#pragma unroll
      for (int mt = 0; mt < 4; ++mt) {
#pragma unroll
        for (int r = 0; r < 4; ++r) {
          const int row = m0 + mt * 16 + quad * 4 + r;
          atomicAdd(&out[(size_t)row * 256 + col], acc[mt][nt][r] + bias);
        }
      }
    }
  }
}

extern "C" void kernel_launch(void* const* d_in, const int* in_sizes, int n_in,
                              void* d_out, int out_size, void* d_ws, size_t ws_size,
                              hipStream_t stream) {
  const float* x   = (const float*)d_in[0];
  const float* W1  = (const float*)d_in[1];
  // d_in[2]=b1, d_in[6]=b2 cancel inside the train-mode batchnorms
  const float* g1  = (const float*)d_in[3];
  const float* be1 = (const float*)d_in[4];
  const float* W2  = (const float*)d_in[5];
  const float* g2  = (const float*)d_in[7];
  const float* be2 = (const float*)d_in[8];
  const float* Wfc = (const float*)d_in[9];
  const float* bfc = (const float*)d_in[10];
  float* out = (float*)d_out;

  char* ws = (char*)d_ws;
  unsigned short* wb = (unsigned short*)ws;                  // 2 MB swizzled bf16 Wfc
  float* pt   = (float*)(ws + (2u << 20));                   // 256 KB [param][d]
  float* ps1  = (float*)(ws + (2u << 20) + (256u << 10));    // 2 MB stats1 partials
  float* ps2s = (float*)(ws + (4u << 20) + (256u << 10));    // 512 KB stats2 sum
  float* ps2q = (float*)(ws + (4u << 20) + (768u << 10));    // 512 KB stats2 sq
  int*   bars = (int*)(ws + (5u << 20) + (256u << 10));      // 16 B counters

  hipMemsetAsync(bars, 0, 4 * sizeof(int), stream);

  k_all<<<dim3(NBLK), dim3(256), 0, stream>>>(
      x, W1, g1, be1, W2, g2, be2, Wfc, bfc,
      wb, pt, ps1, ps2s, ps2q, bars, out);
}

// Round 9
// 204.272 us; speedup vs baseline: 1.4890x; 1.4890x over previous
//
#include <hip/hip_runtime.h>

#define EPSV 1e-5f

typedef short bf16x8 __attribute__((ext_vector_type(8)));
typedef float f32x4 __attribute__((ext_vector_type(4)));

static __device__ __forceinline__ unsigned short f2b(float f) {
  union { float f; unsigned u; } v; v.f = f;
  return (unsigned short)((v.u + 0x7fffu + ((v.u >> 16) & 1u)) >> 16);
}

// ---------- kernel 1: out-zero + Wfc->bf16 swizzle (blk<512) +
//                      x column partial stats (blk 512..575, 64 partials) ----
// wb frag layout: frag=k32b*16+nb; lane(quad,l15): n=nb*16+l15, k=k32b*32+quad*8
__global__ __launch_bounds__(256) void k_pre(const float* __restrict__ wfc,
    unsigned short* __restrict__ wb, const float* __restrict__ x,
    float* __restrict__ ps1, float* __restrict__ out) {
  const int t = threadIdx.x;
  if (blockIdx.x < 512) {
    const int blk = blockIdx.x;
    const size_t gid = (size_t)blk * 256 + t;
    float4 z4 = {0.f, 0.f, 0.f, 0.f};
    float4* ob = (float4*)(out + gid * 16);
#pragma unroll
    for (int j = 0; j < 4; ++j) ob[j] = z4;

    const int f = blk * 256 + t;                         // 0..131071
    const int l15 = f & 15, quad = (f >> 4) & 3, nb = (f >> 6) & 15, k32b = f >> 10;
    const int n = nb * 16 + l15;
    const int k = k32b * 32 + quad * 8;
    const float4* src = (const float4*)(wfc + (size_t)n * 4096 + k);
    float4 a = src[0], b = src[1];
    ushort4 o0, o1;
    o0.x = f2b(a.x); o0.y = f2b(a.y); o0.z = f2b(a.z); o0.w = f2b(a.w);
    o1.x = f2b(b.x); o1.y = f2b(b.y); o1.z = f2b(b.z); o1.w = f2b(b.w);
    *(ushort4*)(wb + (size_t)f * 8) = o0;
    *(ushort4*)(wb + (size_t)f * 8 + 4) = o1;
  } else {
    const int blk = blockIdx.x - 512;                    // 0..63
    const int c = t * 4;
    const int r0 = blk * 128;
    float4 s = {0.f,0.f,0.f,0.f}, q = {0.f,0.f,0.f,0.f};
    for (int g = 0; g < 16; ++g) {
      float4 v[8];
#pragma unroll
      for (int j = 0; j < 8; ++j)
        v[j] = *(const float4*)(x + (size_t)(r0 + g*8 + j) * 1024 + c);
#pragma unroll
      for (int j = 0; j < 8; ++j) {
        s.x += v[j].x; s.y += v[j].y; s.z += v[j].z; s.w += v[j].w;
        q.x = fmaf(v[j].x, v[j].x, q.x); q.y = fmaf(v[j].y, v[j].y, q.y);
        q.z = fmaf(v[j].z, v[j].z, q.z); q.w = fmaf(v[j].w, v[j].w, q.w);
      }
    }
    *(float4*)(ps1 + (size_t)blk * 2048 + c) = s;
    *(float4*)(ps1 + (size_t)blk * 2048 + 1024 + c) = q;
  }
}

// ---------- kernel 2: inline BN1 finalize + layer-2 preact batch stats ------
// grid (32 dgrp, 32 bgrp). Each block re-reduces the 64 ps1 partials for its
// own 32 d (16KB redundant L2 reads — cheaper than a launch). bgrp==0
// publishes s1/t1 to pt rows 0..15.
__global__ __launch_bounds__(256) void k_stats2(const float* __restrict__ x,
    const float* __restrict__ ps1, const float* __restrict__ W1,
    const float* __restrict__ g1, const float* __restrict__ be1,
    const float* __restrict__ W2, float* __restrict__ pt,
    float* __restrict__ ps2s, float* __restrict__ ps2q) {
  __shared__ float rs[8][32], rq[8][32];
  __shared__ float red[8][32][8];
  const int t = threadIdx.x;
  const int dl = t & 31, slot = t >> 5;
  const int d = blockIdx.x * 32 + dl;
  {
    float s0 = 0.f, q0 = 0.f;
#pragma unroll
    for (int u = 0; u < 8; ++u) {
      const size_t base = (size_t)(slot + u * 8) * 2048 + d;
      s0 += ps1[base];
      q0 += ps1[base + 1024];
    }
    rs[slot][dl] = s0; rq[slot][dl] = q0;
  }
  __syncthreads();
  float xs = 0.f, xq = 0.f;
#pragma unroll
  for (int p = 0; p < 8; ++p) { xs += rs[p][dl]; xq += rq[p][dl]; }
  const float inv = 1.f / 8192.f;
  const float mean = xs * inv;
  const float var = xq * inv - mean * mean;
  float s1v[8], t1v[8], w2v[32];
#pragma unroll
  for (int i = 0; i < 8; ++i) {
    const int c = d * 8 + i;
    float w = W1[c];
    s1v[i] = g1[c] * w * rsqrtf(w * w * var + EPSV);
    t1v[i] = be1[c] - s1v[i] * mean;
  }
  if (blockIdx.y == 0 && slot == 0) {
#pragma unroll
    for (int i = 0; i < 8; ++i) {
      pt[i * 1024 + d] = s1v[i];
      pt[(8 + i) * 1024 + d] = t1v[i];
    }
  }
  const float4* wp = (const float4*)(W2 + (size_t)d * 32);
#pragma unroll
  for (int i = 0; i < 8; ++i) {
    float4 v = wp[i];
    w2v[i*4+0]=v.x; w2v[i*4+1]=v.y; w2v[i*4+2]=v.z; w2v[i*4+3]=v.w;
  }
  float s[4] = {0.f,0.f,0.f,0.f}, q[4] = {0.f,0.f,0.f,0.f};
  const int b0 = blockIdx.y * 256 + slot * 32;
  for (int r = 0; r < 32; r += 8) {
    float xv[8];
#pragma unroll
    for (int j = 0; j < 8; ++j)
      xv[j] = x[(size_t)(b0 + r + j) * 1024 + d];
#pragma unroll
    for (int j = 0; j < 8; ++j) {
      float a1[8];
#pragma unroll
      for (int i = 0; i < 8; ++i) a1[i] = fmaxf(fmaf(s1v[i], xv[j], t1v[i]), 0.f);
#pragma unroll
      for (int o = 0; o < 4; ++o) {
        float h = 0.f;
#pragma unroll
        for (int i = 0; i < 8; ++i) h = fmaf(a1[i], w2v[o*8+i], h);
        s[o] += h;
        q[o] = fmaf(h, h, q[o]);
      }
    }
  }
#pragma unroll
  for (int j = 0; j < 4; ++j) {
    red[slot][dl][j] = s[j];
    red[slot][dl][4+j] = q[j];
  }
  __syncthreads();
  const int d2l = t >> 3, j = t & 7;
  float v = 0.f;
#pragma unroll
  for (int p = 0; p < 8; ++p) v += red[p][d2l][j];
  const int c2 = (blockIdx.x * 32 + d2l) * 4 + (t & 3);
  if (j < 4) ps2s[(size_t)blockIdx.y * 4096 + c2] = v;
  else       ps2q[(size_t)blockIdx.y * 4096 + c2] = v;
}

// ---------- kernel 3: reduce + finalize BN2 -> pt rows 16..51 ----------
__global__ void k_fin2(const float* __restrict__ W2, const float* __restrict__ g2,
                       const float* __restrict__ be2, const float* __restrict__ ps2s,
                       const float* __restrict__ ps2q, float* __restrict__ pt) {
  const int c2 = blockIdx.x * 256 + threadIdx.x;         // 0..4095
  const int d = c2 >> 2, o = c2 & 3;
  float sm = 0.f, sq = 0.f;
#pragma unroll
  for (int b = 0; b < 32; ++b) {
    sm += ps2s[(size_t)b * 4096 + c2];
    sq += ps2q[(size_t)b * 4096 + c2];
  }
  const float inv = 1.f / 8192.f;
  float m = sm * inv;
  float var = sq * inv - m * m;
  float s2 = g2[c2] * rsqrtf(var + EPSV);
  float t2 = be2[c2] - s2 * m;
  pt[(48 + o) * 1024 + d] = t2;
#pragma unroll
  for (int i = 0; i < 8; ++i)
    pt[(16 + o * 8 + i) * 1024 + d] = W2[(size_t)d * 32 + o * 8 + i] * s2;
}

// ---------- kernel 4: fused A-gen + GEMM, double-buffered As ----------
// BM=64, BN=256, chunk=32 d, K-split=4; grid (128,4) x 256 -> 2 blocks/CU.
// Per iteration: MFMA(chunk i, buf cur) || A-gen(chunk i+1, buf nxt), ONE
// barrier — VALU and MFMA streams are independent so co-resident waves
// overlap pipes instead of phase-locking.
__global__ __launch_bounds__(256, 2) void k_gemm(const float* __restrict__ x,
    const float* __restrict__ pt, const unsigned short* __restrict__ wb,
    const float* __restrict__ bfc, float* __restrict__ out) {
  // stride 136 shorts = 68 dwords (== 4 mod 32): b128 reads tile banks evenly
  __shared__ __align__(16) unsigned short As[2][64 * 136];   // 34816 B
  const int t = threadIdx.x;
  const int lane = t & 63;
  const int wv = t >> 6;
  const int mt0 = blockIdx.x;
  const int kQ = blockIdx.y;
  const int m0 = mt0 * 64;
  const int d0 = kQ * 256;
  const int quad = lane >> 4;
  const int l15 = lane & 15;
  const int dl = t & 31, bs = t >> 5;
  const int chrot = (mt0 & 1) << 2;

  unsigned short* cur = &As[0][0];
  unsigned short* nxt = &As[1][0];

  f32x4 acc[4][4];
#pragma unroll
  for (int mt = 0; mt < 4; ++mt)
#pragma unroll
    for (int nt = 0; nt < 4; ++nt) {
      f32x4 z = {0.f, 0.f, 0.f, 0.f};
      acc[mt][nt] = z;
    }

  // ---- initial A-gen: chunk order(0) into cur ----
  {
    const int ch = chrot;
    const int d = d0 + ch * 32 + dl;
    float pv[52];
#pragma unroll
    for (int i = 0; i < 52; ++i) pv[i] = pt[i * 1024 + d];
#pragma unroll
    for (int r = 0; r < 8; ++r) {
      const int bl = bs * 8 + r;
      float xv = x[(size_t)(m0 + bl) * 1024 + d];
      float a1[8];
#pragma unroll
      for (int i = 0; i < 8; ++i) a1[i] = fmaxf(fmaf(pv[i], xv, pv[8+i]), 0.f);
      unsigned short o4[4];
#pragma unroll
      for (int o = 0; o < 4; ++o) {
        float h = pv[48 + o];
#pragma unroll
        for (int i = 0; i < 8; ++i) h = fmaf(a1[i], pv[16 + o*8 + i], h);
        o4[o] = f2b(fmaxf(h, 0.f));
      }
      *(ushort4*)&cur[bl * 136 + dl * 4] = make_ushort4(o4[0], o4[1], o4[2], o4[3]);
    }
  }
  __syncthreads();

  for (int chi = 0; chi < 8; ++chi) {
    const int ch = (chi + chrot) & 7;
    const int chn = (chi + 1 + chrot) & 7;
    const int dnx = d0 + chn * 32 + dl;
    // prefetch next chunk's x early (HBM latency hidden under MFMA phase)
    float xv[8];
    if (chi < 7) {
#pragma unroll
      for (int r = 0; r < 8; ++r)
        xv[r] = x[(size_t)(m0 + bs * 8 + r) * 1024 + dnx];
    }
    // ---- MFMA phase from cur ----
#pragma unroll
    for (int kk = 0; kk < 4; ++kk) {
      bf16x8 af[4];
#pragma unroll
      for (int mt = 0; mt < 4; ++mt)
        af[mt] = *(const bf16x8*)&cur[(mt*16 + l15) * 136 + kk*32 + quad*8];
      const int k32b = kQ * 32 + ch * 4 + kk;
#pragma unroll
      for (int nt = 0; nt < 4; ++nt) {
        const int frag = k32b * 16 + wv * 4 + nt;
        bf16x8 bfr = *(const bf16x8*)&wb[((size_t)frag * 64 + lane) * 8];
#pragma unroll
        for (int mt = 0; mt < 4; ++mt)
          acc[mt][nt] = __builtin_amdgcn_mfma_f32_16x16x32_bf16(af[mt], bfr,
                                                                acc[mt][nt], 0, 0, 0);
      }
    }
    // ---- A-gen next chunk into nxt (independent of MFMA above) ----
    if (chi < 7) {
      float pv[52];
#pragma unroll
      for (int i = 0; i < 52; ++i) pv[i] = pt[i * 1024 + dnx];
#pragma unroll
      for (int r = 0; r < 8; ++r) {
        const int bl = bs * 8 + r;
        float a1[8];
#pragma unroll
        for (int i = 0; i < 8; ++i) a1[i] = fmaxf(fmaf(pv[i], xv[r], pv[8+i]), 0.f);
        unsigned short o4[4];
#pragma unroll
        for (int o = 0; o < 4; ++o) {
          float h = pv[48 + o];
#pragma unroll
          for (int i = 0; i < 8; ++i) h = fmaf(a1[i], pv[16 + o*8 + i], h);
          o4[o] = f2b(fmaxf(h, 0.f));
        }
        *(ushort4*)&nxt[bl * 136 + dl * 4] = make_ushort4(o4[0], o4[1], o4[2], o4[3]);
      }
    }
    __syncthreads();
    unsigned short* tmp = cur; cur = nxt; nxt = tmp;
  }
  // ---- epilogue: atomic merge of 4 K-splits; split 0 adds bias ----
#pragma unroll
  for (int nt = 0; nt < 4; ++nt) {
    const int col = wv * 64 + nt * 16 + l15;
    const float bias = (kQ == 0) ? bfc[col] : 0.f;
#pragma unroll
    for (int mt = 0; mt < 4; ++mt) {
#pragma unroll
      for (int r = 0; r < 4; ++r) {
        const int row = m0 + mt * 16 + quad * 4 + r;
        atomicAdd(&out[(size_t)row * 256 + col], acc[mt][nt][r] + bias);
      }
    }
  }
}

extern "C" void kernel_launch(void* const* d_in, const int* in_sizes, int n_in,
                              void* d_out, int out_size, void* d_ws, size_t ws_size,
                              hipStream_t stream) {
  const float* x   = (const float*)d_in[0];
  const float* W1  = (const float*)d_in[1];
  // d_in[2]=b1, d_in[6]=b2 cancel inside the train-mode batchnorms
  const float* g1  = (const float*)d_in[3];
  const float* be1 = (const float*)d_in[4];
  const float* W2  = (const float*)d_in[5];
  const float* g2  = (const float*)d_in[7];
  const float* be2 = (const float*)d_in[8];
  const float* Wfc = (const float*)d_in[9];
  const float* bfc = (const float*)d_in[10];
  float* out = (float*)d_out;

  char* ws = (char*)d_ws;
  unsigned short* wb = (unsigned short*)ws;                  // 2 MB swizzled bf16 Wfc
  float* pt   = (float*)(ws + (2u << 20));                   // 256 KB [param][d]
  float* ps1  = (float*)(ws + (2u << 20) + (256u << 10));    // 512 KB stats1 partials
  float* ps2s = (float*)(ws + (2u << 20) + (768u << 10));    // 512 KB stats2 sum
  float* ps2q = (float*)(ws + (2u << 20) + (1280u << 10));   // 512 KB stats2 sq

  k_pre   <<<dim3(576),    256, 0, stream>>>(Wfc, wb, x, ps1, out);
  k_stats2<<<dim3(32, 32), 256, 0, stream>>>(x, ps1, W1, g1, be1, W2, pt, ps2s, ps2q);
  k_fin2  <<<dim3(16),     256, 0, stream>>>(W2, g2, be2, ps2s, ps2q, pt);
  k_gemm  <<<dim3(128, 4), 256, 0, stream>>>(x, pt, wb, bfc, out);
}